// Round 2
// baseline (3169.163 us; speedup 1.0000x reference)
//
#include <hip/hip_runtime.h>
#include <cstdint>
#include <cstddef>

#define B_DIM   4096
#define IN_DIM  2048
#define OUT_DIM 4096

typedef __attribute__((ext_vector_type(8))) __bf16 bf16x8;
typedef __attribute__((ext_vector_type(4))) float  f32x4;

__device__ __forceinline__ unsigned short f2bf(float f) {
    unsigned int u = __float_as_uint(f);
    u += 0x7FFFu + ((u >> 16) & 1u);          // round-to-nearest-even
    return (unsigned short)(u >> 16);
}
__device__ __forceinline__ float bf2f(unsigned short b) {
    return __uint_as_float(((unsigned int)b) << 16);
}

// global -> LDS direct DMA, 16 B per lane. Dest is wave-uniform base; HW writes
// lane i at base + i*16. Proper addrspacecast (NOT uintptr_t truncation).
__device__ __forceinline__ void gload16(const void* g, void* l) {
    __builtin_amdgcn_global_load_lds(
        (const __attribute__((address_space(1))) void*)g,
        (__attribute__((address_space(3))) void*)l, 16, 0, 0);
}

// G0 = bf16(-0.05 * sqrt(in^2 + 1e-6))   (step-0 gradient source: x=0 -> exp(-u)=1)
__global__ void prep_g0_kernel(const float* __restrict__ in, unsigned short* __restrict__ Gb) {
    int i = blockIdx.x * 256 + threadIdx.x;   // indexes float4
    float4 v = reinterpret_cast<const float4*>(in)[i];
    ushort4 g;
    g.x = f2bf(-0.05f * sqrtf(v.x * v.x + 1e-6f));
    g.y = f2bf(-0.05f * sqrtf(v.y * v.y + 1e-6f));
    g.z = f2bf(-0.05f * sqrtf(v.z * v.z + 1e-6f));
    g.w = f2bf(-0.05f * sqrtf(v.w * v.w + 1e-6f));
    reinterpret_cast<ushort4*>(Gb)[i] = g;
}

// Wb = bf16(W) [OUT][IN];  WTb = bf16(W^T) [IN][OUT]  (tiled LDS transpose)
__global__ void conv_w_kernel(const float* __restrict__ W, unsigned short* __restrict__ Wb,
                              unsigned short* __restrict__ WTb) {
    __shared__ float tile[64][65];
    const int i0 = blockIdx.x * 64;   // IN direction
    const int j0 = blockIdx.y * 64;   // OUT direction
    const int c  = threadIdx.x & 63;
    const int rq = threadIdx.x >> 6;
#pragma unroll
    for (int rp = 0; rp < 16; ++rp) {
        int row = rp * 4 + rq;
        float w = W[(size_t)(j0 + row) * IN_DIM + i0 + c];
        tile[row][c] = w;
        Wb[(size_t)(j0 + row) * IN_DIM + i0 + c] = f2bf(w);
    }
    __syncthreads();
#pragma unroll
    for (int rp = 0; rp < 16; ++rp) {
        int row = rp * 4 + rq;
        WTb[(size_t)(i0 + row) * OUT_DIM + j0 + c] = f2bf(tile[c][row]);
    }
}

// NT GEMM: C[M,N] = A[M,K] * Bm[N,K]^T, bf16 in, fp32 acc. m97 structure:
// 128x128 tile, 4 waves (2x2 of 64x64), BK=32, global_load_lds(16B), LINEAR LDS,
// 2 barriers per K-step. Fused epilogues:
//  EPI 0: Gb = bf16(-0.05 * a * exp(-acc)),  a = sqrt(in^2+1e-6) recomputed
//  EPI 1: out = 0.05 * (1 + exp(-acc)) * a
//  EPI 2: fused RMSProp + prox update of x/acc1/acc2 (+ xb bf16 mirror)
template <int EPI>
__global__ __launch_bounds__(256, 2)
void gemm_nt(const unsigned short* __restrict__ A, const unsigned short* __restrict__ Bm,
             int N, int K,
             const float* __restrict__ inb, unsigned short* __restrict__ Gb,
             float* __restrict__ out,
             float* __restrict__ x, unsigned short* __restrict__ acc1,
             float* __restrict__ acc2, unsigned short* __restrict__ xb) {
    __shared__ alignas(16) char smem[16384];      // A tile [0,8K), B tile [8K,16K)
    const int tid  = threadIdx.x;
    const int lane = tid & 63;
    const int w    = tid >> 6;
    const int nbx  = N >> 7;
    const int bx   = blockIdx.x % nbx;
    const int by   = blockIdx.x / nbx;
    const int row0 = by << 7;
    const int col0 = bx << 7;

    // staging: wave w covers rows w*16..w*16+15 (and +64); lane l -> row w*16+(l>>2),
    // 16B slot (l&3). LDS layout is linear [row][64B of K].
    const int q     = lane >> 2;
    const int s     = lane & 3;
    const int rowS0 = w * 16 + q;
    const size_t strideK2 = (size_t)K * 2;
    const char* Ab = (const char*)A;
    const char* Bb = (const char*)Bm;
    const char* gA0 = Ab + (size_t)(row0 + rowS0)      * strideK2 + s * 16;
    const char* gA1 = Ab + (size_t)(row0 + rowS0 + 64) * strideK2 + s * 16;
    const char* gB0 = Bb + (size_t)(col0 + rowS0)      * strideK2 + s * 16;
    const char* gB1 = Bb + (size_t)(col0 + rowS0 + 64) * strideK2 + s * 16;
    char* lA0 = smem + w * 1024;
    char* lA1 = smem + 4096  + w * 1024;
    char* lB0 = smem + 8192  + w * 1024;
    char* lB1 = smem + 12288 + w * 1024;

    // fragment read offsets (linear): row*64 + (lane>>4)*16
    const int wm = w >> 1, wn = w & 1;
    int aOff[4], bOff[4];
#pragma unroll
    for (int m = 0; m < 4; ++m) {
        aOff[m] = (wm * 64 + m * 16 + (lane & 15)) * 64 + ((lane >> 4) * 16);
        bOff[m] = 8192 + (wn * 64 + m * 16 + (lane & 15)) * 64 + ((lane >> 4) * 16);
    }

    f32x4 acc[4][4] = {};

    for (int k0 = 0; k0 < K; k0 += 32) {
        const size_t kb = (size_t)k0 * 2;
        gload16(gA0 + kb, lA0);
        gload16(gA1 + kb, lA1);
        gload16(gB0 + kb, lB0);
        gload16(gB1 + kb, lB1);
        __syncthreads();                       // compiler drains vmcnt before s_barrier
        bf16x8 aF[4], bF[4];
#pragma unroll
        for (int m = 0; m < 4; ++m) aF[m] = *reinterpret_cast<const bf16x8*>(smem + aOff[m]);
#pragma unroll
        for (int n = 0; n < 4; ++n) bF[n] = *reinterpret_cast<const bf16x8*>(smem + bOff[n]);
#pragma unroll
        for (int m = 0; m < 4; ++m)
#pragma unroll
            for (int n = 0; n < 4; ++n)
                acc[m][n] = __builtin_amdgcn_mfma_f32_16x16x32_bf16(aF[m], bF[n], acc[m][n], 0, 0, 0);
        __syncthreads();
    }

    // C layout (m89-verified): col = lane&15, row = (lane>>4)*4 + i
    const int rl = (lane >> 4) << 2;
    const int cl = lane & 15;
#pragma unroll
    for (int m = 0; m < 4; ++m) {
#pragma unroll
        for (int n = 0; n < 4; ++n) {
            const int rb = row0 + wm * 64 + m * 16 + rl;
            const int cc = col0 + wn * 64 + n * 16 + cl;
#pragma unroll
            for (int i = 0; i < 4; ++i) {
                const size_t idx = (size_t)(rb + i) * N + cc;
                const float v = acc[m][n][i];
                if constexpr (EPI == 0) {
                    float iv = inb[idx];
                    float av = sqrtf(iv * iv + 1e-6f);
                    Gb[idx] = f2bf(-0.05f * av * expf(-v));
                } else if constexpr (EPI == 1) {
                    float iv = inb[idx];
                    float av = sqrtf(iv * iv + 1e-6f);
                    out[idx] = 0.05f * (1.0f + expf(-v)) * av;
                } else {
                    float xv   = x[idx];
                    float g    = v + 0.02f * xv + 0.1f * xv * rsqrtf(xv * xv + 1e-6f);
                    float a1   = 0.9f * bf2f(acc1[idx]) + 0.1f * g * g;
                    float inv  = rsqrtf(a1 + 1e-8f);
                    float r_   = 0.009f * g * inv;
                    float a2   = 0.9f * acc2[idx] - r_;
                    float cand = xv - r_;
                    float t    = 0.0009f * inv;
                    float xn   = fmaxf(cand - t, 0.0f) + fminf(cand + t, 0.0f) + 0.9f * a2;
                    acc1[idx] = f2bf(a1);
                    acc2[idx] = a2;
                    x[idx]    = xn;
                    xb[idx]   = f2bf(xn);
                }
            }
        }
    }
}

extern "C" void kernel_launch(void* const* d_in, const int* in_sizes, int n_in,
                              void* d_out, int out_size, void* d_ws, size_t ws_size,
                              hipStream_t stream) {
    const float* in = (const float*)d_in[0];
    const float* W  = (const float*)d_in[1];
    float* out = (float*)d_out;
    char* ws = (char*)d_ws;

    // workspace layout — 240 MB total
    float*          x    = (float*)(ws);                           // 64 MB fp32 [4096,4096]
    float*          acc2 = (float*)(ws + ((size_t)64  << 20));     // 64 MB fp32
    unsigned short* acc1 = (unsigned short*)(ws + ((size_t)128 << 20)); // 32 MB bf16
    unsigned short* xb   = (unsigned short*)(ws + ((size_t)160 << 20)); // 32 MB bf16 [4096,4096]
    unsigned short* Wb   = (unsigned short*)(ws + ((size_t)192 << 20)); // 16 MB bf16 [4096,2048]
    unsigned short* WTb  = (unsigned short*)(ws + ((size_t)208 << 20)); // 16 MB bf16 [2048,4096]
    unsigned short* Gb   = (unsigned short*)(ws + ((size_t)224 << 20)); // 16 MB bf16 [4096,2048]

    hipMemsetAsync(ws, 0, (size_t)160 << 20, stream);   // x, acc2, acc1 = 0

    prep_g0_kernel<<<dim3(B_DIM * IN_DIM / 4 / 256), dim3(256), 0, stream>>>(in, Gb);
    conv_w_kernel<<<dim3(IN_DIM / 64, OUT_DIM / 64), dim3(256), 0, stream>>>(W, Wb, WTb);

    const int gridFwd  = (IN_DIM / 128) * (B_DIM / 128);   // 512 blocks
    const int gridGrad = (OUT_DIM / 128) * (B_DIM / 128);  // 1024 blocks

    for (int step = 0; step < 9; ++step) {
        if (step > 0) {
            // u = x @ W  (A = xb [B,OUT]; Bm = WTb [IN,OUT]) -> Gb = -0.05*a*exp(-u)
            gemm_nt<0><<<dim3(gridFwd), dim3(256), 0, stream>>>(
                xb, WTb, IN_DIM, OUT_DIM, in, Gb, nullptr, nullptr, nullptr, nullptr, nullptr);
        }
        // gmat = G @ W^T (A = Gb [B,IN]; Bm = Wb [OUT,IN]) -> fused state update
        gemm_nt<2><<<dim3(gridGrad), dim3(256), 0, stream>>>(
            Gb, Wb, OUT_DIM, IN_DIM, nullptr, nullptr, nullptr, x, acc1, acc2, xb);
    }
    // final: out = 0.05*(1+exp(-x@W))*a
    gemm_nt<1><<<dim3(gridFwd), dim3(256), 0, stream>>>(
        xb, WTb, IN_DIM, OUT_DIM, in, nullptr, out, nullptr, nullptr, nullptr, nullptr);
}

// Round 3
// 1868.580 us; speedup vs baseline: 1.6960x; 1.6960x over previous
//
#include <hip/hip_runtime.h>
#include <cstdint>
#include <cstddef>

#define B_DIM   4096
#define IN_DIM  2048
#define OUT_DIM 4096

typedef __attribute__((ext_vector_type(8))) __bf16 bf16x8;
typedef __attribute__((ext_vector_type(4))) float  f32x4;

__device__ __forceinline__ unsigned short f2bf(float f) {
    unsigned int u = __float_as_uint(f);
    u += 0x7FFFu + ((u >> 16) & 1u);          // round-to-nearest-even
    return (unsigned short)(u >> 16);
}
__device__ __forceinline__ float bf2f(unsigned short b) {
    return __uint_as_float(((unsigned int)b) << 16);
}

// global -> LDS direct DMA, 16 B per lane (wave-uniform LDS base, lane i at +i*16).
__device__ __forceinline__ void gload16(const void* g, void* l) {
    __builtin_amdgcn_global_load_lds(
        (const __attribute__((address_space(1))) void*)g,
        (__attribute__((address_space(3))) void*)l, 16, 0, 0);
}

// G0 = bf16(-0.05 * sqrt(in^2 + 1e-6))   (step-0 gradient source: x=0 -> exp(-u)=1)
__global__ void prep_g0_kernel(const float* __restrict__ in, unsigned short* __restrict__ Gb) {
    int i = blockIdx.x * 256 + threadIdx.x;   // indexes float4
    float4 v = reinterpret_cast<const float4*>(in)[i];
    ushort4 g;
    g.x = f2bf(-0.05f * sqrtf(v.x * v.x + 1e-6f));
    g.y = f2bf(-0.05f * sqrtf(v.y * v.y + 1e-6f));
    g.z = f2bf(-0.05f * sqrtf(v.z * v.z + 1e-6f));
    g.w = f2bf(-0.05f * sqrtf(v.w * v.w + 1e-6f));
    reinterpret_cast<ushort4*>(Gb)[i] = g;
}

// Wb = bf16(W) [OUT][IN];  WTb = bf16(W^T) [IN][OUT]  (tiled LDS transpose)
__global__ void conv_w_kernel(const float* __restrict__ W, unsigned short* __restrict__ Wb,
                              unsigned short* __restrict__ WTb) {
    __shared__ float tile[64][65];
    const int i0 = blockIdx.x * 64;   // IN direction
    const int j0 = blockIdx.y * 64;   // OUT direction
    const int c  = threadIdx.x & 63;
    const int rq = threadIdx.x >> 6;
#pragma unroll
    for (int rp = 0; rp < 16; ++rp) {
        int row = rp * 4 + rq;
        float w = W[(size_t)(j0 + row) * IN_DIM + i0 + c];
        tile[row][c] = w;
        Wb[(size_t)(j0 + row) * IN_DIM + i0 + c] = f2bf(w);
    }
    __syncthreads();
#pragma unroll
    for (int rp = 0; rp < 16; ++rp) {
        int row = rp * 4 + rq;
        WTb[(size_t)(i0 + row) * OUT_DIM + j0 + c] = f2bf(tile[c][row]);
    }
}

// NT GEMM: C[M,N] = A[M,K] * Bm[N,K]^T, bf16 in, fp32 acc. m97 structure:
// 128x128 tile, 4 waves (2x2 of 64x64), BK=32, global_load_lds(16B), linear LDS.
// Epilogue staged through LDS ([16][68] f32 per wave) so all global state I/O is
// float4 / ushort4 row-contiguous (256 B per 16-lane group).
//  EPI 0: Gb = bf16(-0.05 * a * exp(-acc)),  a = sqrt(in^2+1e-6) recomputed
//  EPI 1: out = 0.05 * (1 + exp(-acc)) * a
//  EPI 2: fused RMSProp + prox update of x (fp32) / acc1,acc2 (bf16) + xb mirror
template <int EPI>
__global__ __launch_bounds__(256, 2)
void gemm_nt(const unsigned short* __restrict__ A, const unsigned short* __restrict__ Bm,
             int N, int K,
             const float* __restrict__ inb, unsigned short* __restrict__ Gb,
             float* __restrict__ out,
             float* __restrict__ x, unsigned short* __restrict__ acc1,
             unsigned short* __restrict__ acc2, unsigned short* __restrict__ xb) {
    __shared__ alignas(16) char smem[17408];      // K-loop: [0,16K); epilogue: 4x4352B
    const int tid  = threadIdx.x;
    const int lane = tid & 63;
    const int w    = tid >> 6;
    const int nbx  = N >> 7;
    // XCD-aware bijective swizzle (grid is a multiple of 8)
    const int nwg  = gridDim.x;
    const int cpx  = nwg >> 3;
    const int bid  = (int)blockIdx.x;
    const int swz  = (bid & 7) * cpx + (bid >> 3);
    const int bx   = swz % nbx;
    const int by   = swz / nbx;
    const int row0 = by << 7;
    const int col0 = bx << 7;

    // staging: wave w covers rows w*16..w*16+15 (and +64); lane l -> row w*16+(l>>2),
    // 16B slot (l&3). LDS layout linear [row][64B of K].
    const int q     = lane >> 2;
    const int s     = lane & 3;
    const int rowS0 = w * 16 + q;
    const size_t strideK2 = (size_t)K * 2;
    const char* Ab = (const char*)A;
    const char* Bb = (const char*)Bm;
    const char* gA0 = Ab + (size_t)(row0 + rowS0)      * strideK2 + s * 16;
    const char* gA1 = Ab + (size_t)(row0 + rowS0 + 64) * strideK2 + s * 16;
    const char* gB0 = Bb + (size_t)(col0 + rowS0)      * strideK2 + s * 16;
    const char* gB1 = Bb + (size_t)(col0 + rowS0 + 64) * strideK2 + s * 16;
    char* lA0 = smem + w * 1024;
    char* lA1 = smem + 4096  + w * 1024;
    char* lB0 = smem + 8192  + w * 1024;
    char* lB1 = smem + 12288 + w * 1024;

    // fragment read offsets (linear): row*64 + (lane>>4)*16
    const int wm = w >> 1, wn = w & 1;
    int aOff[4], bOff[4];
#pragma unroll
    for (int m = 0; m < 4; ++m) {
        aOff[m] = (wm * 64 + m * 16 + (lane & 15)) * 64 + ((lane >> 4) * 16);
        bOff[m] = 8192 + (wn * 64 + m * 16 + (lane & 15)) * 64 + ((lane >> 4) * 16);
    }

    f32x4 acc[4][4] = {};

    for (int k0 = 0; k0 < K; k0 += 32) {
        const size_t kb = (size_t)k0 * 2;
        gload16(gA0 + kb, lA0);
        gload16(gA1 + kb, lA1);
        gload16(gB0 + kb, lB0);
        gload16(gB1 + kb, lB1);
        __syncthreads();                       // compiler drains vmcnt before s_barrier
        bf16x8 aF[4], bF[4];
#pragma unroll
        for (int m = 0; m < 4; ++m) aF[m] = *reinterpret_cast<const bf16x8*>(smem + aOff[m]);
#pragma unroll
        for (int n = 0; n < 4; ++n) bF[n] = *reinterpret_cast<const bf16x8*>(smem + bOff[n]);
#pragma unroll
        for (int m = 0; m < 4; ++m)
#pragma unroll
            for (int n = 0; n < 4; ++n)
                acc[m][n] = __builtin_amdgcn_mfma_f32_16x16x32_bf16(aF[m], bF[n], acc[m][n], 0, 0, 0);
        __syncthreads();                       // also protects epilogue LDS reuse
    }

    // ---- epilogue: per-wave LDS re-layout for coalesced I/O ----
    // MFMA C layout (m89): value acc[m][n][i] is row (lane>>4)*4+i, col n*16+(lane&15)
    float* lep = (float*)(smem + w * 4352);    // [16][68] f32, 16B-aligned rows
    const int li = lane >> 4;                  // 0..3
    const int lc = lane & 15;                  // 0..15
    const int row0w = row0 + wm * 64;
    const int col0w = col0 + wn * 64;
#pragma unroll
    for (int m = 0; m < 4; ++m) {
#pragma unroll
        for (int n = 0; n < 4; ++n)
#pragma unroll
            for (int i = 0; i < 4; ++i)
                lep[(li * 4 + i) * 68 + n * 16 + lc] = acc[m][n][i];
        // per-wave private region; same-wave DS ordering via lgkmcnt (compiler)
#pragma unroll
        for (int rr = 0; rr < 4; ++rr) {
            const int row = rr + li * 4;                    // 16-lane group: one row
            float4 v = *reinterpret_cast<const float4*>(&lep[row * 68 + lc * 4]);
            const size_t idx  = (size_t)(row0w + m * 16 + row) * N + col0w + lc * 4;
            const size_t idx4 = idx >> 2;
            if constexpr (EPI == 0) {
                float4 iv = reinterpret_cast<const float4*>(inb)[idx4];
                ushort4 g;
                g.x = f2bf(-0.05f * sqrtf(iv.x * iv.x + 1e-6f) * expf(-v.x));
                g.y = f2bf(-0.05f * sqrtf(iv.y * iv.y + 1e-6f) * expf(-v.y));
                g.z = f2bf(-0.05f * sqrtf(iv.z * iv.z + 1e-6f) * expf(-v.z));
                g.w = f2bf(-0.05f * sqrtf(iv.w * iv.w + 1e-6f) * expf(-v.w));
                *reinterpret_cast<ushort4*>(&Gb[idx]) = g;
            } else if constexpr (EPI == 1) {
                float4 iv = reinterpret_cast<const float4*>(inb)[idx4];
                float4 o;
                o.x = 0.05f * (1.0f + expf(-v.x)) * sqrtf(iv.x * iv.x + 1e-6f);
                o.y = 0.05f * (1.0f + expf(-v.y)) * sqrtf(iv.y * iv.y + 1e-6f);
                o.z = 0.05f * (1.0f + expf(-v.z)) * sqrtf(iv.z * iv.z + 1e-6f);
                o.w = 0.05f * (1.0f + expf(-v.w)) * sqrtf(iv.w * iv.w + 1e-6f);
                reinterpret_cast<float4*>(out)[idx4] = o;
            } else {
                float4  xv  = reinterpret_cast<const float4*>(x)[idx4];
                ushort4 a1u = *reinterpret_cast<const ushort4*>(&acc1[idx]);
                ushort4 a2u = *reinterpret_cast<const ushort4*>(&acc2[idx]);
                float xs[4] = {xv.x, xv.y, xv.z, xv.w};
                float vs[4] = {v.x, v.y, v.z, v.w};
                unsigned short a1s[4] = {a1u.x, a1u.y, a1u.z, a1u.w};
                unsigned short a2s[4] = {a2u.x, a2u.y, a2u.z, a2u.w};
                float xn4[4]; unsigned short a1n[4], a2n[4], xbn[4];
#pragma unroll
                for (int j = 0; j < 4; ++j) {
                    float g    = vs[j] + 0.02f * xs[j] + 0.1f * xs[j] * rsqrtf(xs[j] * xs[j] + 1e-6f);
                    float a1   = 0.9f * bf2f(a1s[j]) + 0.1f * g * g;
                    float inv  = rsqrtf(a1 + 1e-8f);
                    float r_   = 0.009f * g * inv;
                    float a2   = 0.9f * bf2f(a2s[j]) - r_;
                    float cand = xs[j] - r_;
                    float t    = 0.0009f * inv;
                    float xn   = fmaxf(cand - t, 0.0f) + fminf(cand + t, 0.0f) + 0.9f * a2;
                    xn4[j] = xn; a1n[j] = f2bf(a1); a2n[j] = f2bf(a2); xbn[j] = f2bf(xn);
                }
                float4 xo = {xn4[0], xn4[1], xn4[2], xn4[3]};
                reinterpret_cast<float4*>(x)[idx4] = xo;
                *reinterpret_cast<ushort4*>(&acc1[idx]) = make_ushort4(a1n[0], a1n[1], a1n[2], a1n[3]);
                *reinterpret_cast<ushort4*>(&acc2[idx]) = make_ushort4(a2n[0], a2n[1], a2n[2], a2n[3]);
                *reinterpret_cast<ushort4*>(&xb[idx])   = make_ushort4(xbn[0], xbn[1], xbn[2], xbn[3]);
            }
        }
    }
}

extern "C" void kernel_launch(void* const* d_in, const int* in_sizes, int n_in,
                              void* d_out, int out_size, void* d_ws, size_t ws_size,
                              hipStream_t stream) {
    const float* in = (const float*)d_in[0];
    const float* W  = (const float*)d_in[1];
    float* out = (float*)d_out;
    char* ws = (char*)d_ws;

    // workspace layout — 208 MB total
    float*          x    = (float*)(ws);                                 // 64 MB fp32 [4096,4096]
    unsigned short* acc1 = (unsigned short*)(ws + ((size_t)64  << 20));  // 32 MB bf16
    unsigned short* acc2 = (unsigned short*)(ws + ((size_t)96  << 20));  // 32 MB bf16
    unsigned short* xb   = (unsigned short*)(ws + ((size_t)128 << 20));  // 32 MB bf16 [4096,4096]
    unsigned short* Wb   = (unsigned short*)(ws + ((size_t)160 << 20));  // 16 MB bf16 [4096,2048]
    unsigned short* WTb  = (unsigned short*)(ws + ((size_t)176 << 20));  // 16 MB bf16 [2048,4096]
    unsigned short* Gb   = (unsigned short*)(ws + ((size_t)192 << 20));  // 16 MB bf16 [4096,2048]

    hipMemsetAsync(ws, 0, (size_t)128 << 20, stream);   // x, acc1, acc2 = 0

    prep_g0_kernel<<<dim3(B_DIM * IN_DIM / 4 / 256), dim3(256), 0, stream>>>(in, Gb);
    conv_w_kernel<<<dim3(IN_DIM / 64, OUT_DIM / 64), dim3(256), 0, stream>>>(W, Wb, WTb);

    const int gridFwd  = (IN_DIM / 128) * (B_DIM / 128);   // 512 blocks
    const int gridGrad = (OUT_DIM / 128) * (B_DIM / 128);  // 1024 blocks

    for (int step = 0; step < 9; ++step) {
        if (step > 0) {
            // u = x @ W  (A = xb [B,OUT]; Bm = WTb [IN,OUT]) -> Gb = -0.05*a*exp(-u)
            gemm_nt<0><<<dim3(gridFwd), dim3(256), 0, stream>>>(
                xb, WTb, IN_DIM, OUT_DIM, in, Gb, nullptr, nullptr, nullptr, nullptr, nullptr);
        }
        // gmat = G @ W^T (A = Gb [B,IN]; Bm = Wb [OUT,IN]) -> fused state update
        gemm_nt<2><<<dim3(gridGrad), dim3(256), 0, stream>>>(
            Gb, Wb, OUT_DIM, IN_DIM, nullptr, nullptr, nullptr, x, acc1, acc2, xb);
    }
    // final: out = 0.05*(1+exp(-x@W))*a
    gemm_nt<1><<<dim3(gridFwd), dim3(256), 0, stream>>>(
        xb, WTb, IN_DIM, OUT_DIM, in, nullptr, out, nullptr, nullptr, nullptr, nullptr);
}

// Round 4
// 1716.199 us; speedup vs baseline: 1.8466x; 1.0888x over previous
//
#include <hip/hip_runtime.h>
#include <cstdint>
#include <cstddef>

#define B_DIM   4096
#define IN_DIM  2048
#define OUT_DIM 4096

typedef __attribute__((ext_vector_type(8))) __bf16 bf16x8;
typedef __attribute__((ext_vector_type(4))) float  f32x4;
typedef unsigned short ushortT;

__device__ __forceinline__ ushortT f2bf(float f) {
    unsigned int u = __float_as_uint(f);
    u += 0x7FFFu + ((u >> 16) & 1u);          // round-to-nearest-even
    return (ushortT)(u >> 16);
}
__device__ __forceinline__ float bf2f(ushortT b) {
    return __uint_as_float(((unsigned int)b) << 16);
}

// global -> LDS direct DMA, 16 B per lane (wave-uniform LDS base, lane i at +i*16).
__device__ __forceinline__ void gload16(const void* g, void* l) {
    __builtin_amdgcn_global_load_lds(
        (const __attribute__((address_space(1))) void*)g,
        (__attribute__((address_space(3))) void*)l, 16, 0, 0);
}

// G0 = bf16(-0.05 * sqrt(in^2 + 1e-6))   (step-0 gradient: x=0 -> exp(-u)=1)
__global__ void prep_g0_kernel(const float* __restrict__ in, ushortT* __restrict__ Gb) {
    int i = blockIdx.x * 256 + threadIdx.x;
    float4 v = reinterpret_cast<const float4*>(in)[i];
    ushort4 g;
    g.x = f2bf(-0.05f * sqrtf(v.x * v.x + 1e-6f));
    g.y = f2bf(-0.05f * sqrtf(v.y * v.y + 1e-6f));
    g.z = f2bf(-0.05f * sqrtf(v.z * v.z + 1e-6f));
    g.w = f2bf(-0.05f * sqrtf(v.w * v.w + 1e-6f));
    reinterpret_cast<ushort4*>(Gb)[i] = g;
}

// Wb = bf16(W) [OUT][IN];  WTb = bf16(W^T) [IN][OUT]
__global__ void conv_w_kernel(const float* __restrict__ W, ushortT* __restrict__ Wb,
                              ushortT* __restrict__ WTb) {
    __shared__ float tile[64][65];
    const int i0 = blockIdx.x * 64;
    const int j0 = blockIdx.y * 64;
    const int c  = threadIdx.x & 63;
    const int rq = threadIdx.x >> 6;
#pragma unroll
    for (int rp = 0; rp < 16; ++rp) {
        int row = rp * 4 + rq;
        float w = W[(size_t)(j0 + row) * IN_DIM + i0 + c];
        tile[row][c] = w;
        Wb[(size_t)(j0 + row) * IN_DIM + i0 + c] = f2bf(w);
    }
    __syncthreads();
#pragma unroll
    for (int rp = 0; rp < 16; ++rp) {
        int row = rp * 4 + rq;
        WTb[(size_t)(i0 + row) * OUT_DIM + j0 + c] = f2bf(tile[c][row]);
    }
}

// ============================================================================
// Ring-pipelined NT GEMM: C[M,N] = A[M,K]*Bm[N,K]^T, bf16 in / fp32 acc.
// BN=256, BK=32, 8 waves (2M x 4N), 512 threads. Depth-4 LDS ring of K-tiles,
// staged 3 ahead via global_load_lds; counted s_waitcnt vmcnt(3L) (never 0 in
// steady loop). LDS XOR-swizzle slot^=(row>>1)&3 on 16B slots (inverse-swizzled
// global source, swizzled ds_read) -> fragment reads 2-way max (free).
// Race proof: iter t writes slot (t+3)&3, last read by tile t-1 whose ds_reads
// retired before barrier B1; vmcnt(3L)+B2 publishes tile t to all waves.
// Epilogue: per-wave LDS re-layout ([16][68] f32) -> coalesced float4/ushort4.
//  EPI 0: Gb = bf16(-0.05*a*exp(-acc));  EPI 1: out = 0.05*(1+exp(-acc))*a;
//  EPI 2: fused RMSProp + prox update of x (fp32), acc1/acc2 (bf16), xb mirror.
// ============================================================================
template <int EPI, int BM>
__global__ __launch_bounds__(512, 2)
void gemm_ring(const ushortT* __restrict__ A, const ushortT* __restrict__ Bm,
               int N, int K,
               const float* __restrict__ inb, ushortT* __restrict__ Gb,
               float* __restrict__ out,
               float* __restrict__ x, ushortT* __restrict__ acc1,
               ushortT* __restrict__ acc2, ushortT* __restrict__ xb) {
    constexpr int BN   = 256;
    constexpr int ASZ  = BM * 64;          // A K-slab bytes (BM x 32 bf16)
    constexpr int BSZ  = BN * 64;          // 16384
    constexpr int SLOT = ASZ + BSZ;
    constexpr int LA   = BM / 128;         // gload issues/thread for A (1 or 2)
    constexpr int LB   = BN / 128;         // 2
    constexpr int L    = LA + LB;          // 3 (BM=128) or 4 (BM=256)
    constexpr int MR   = BM / 32;          // per-wave M fragments (4 or 8)
    __shared__ alignas(16) char smem[4 * SLOT];

    const int tid  = threadIdx.x;
    const int lane = tid & 63;
    const int w    = tid >> 6;
    const int wm   = w >> 2;               // 0..1
    const int wn   = w & 3;                // 0..3
    const int nbx  = N / BN;
    const int nwg  = gridDim.x;            // 256 for all uses (multiple of 8)
    const int cpx  = nwg >> 3;
    const int bid  = (int)blockIdx.x;
    const int swz  = (bid & 7) * cpx + (bid >> 3);   // XCD-aware bijective
    const int bx   = swz % nbx;
    const int by   = swz / nbx;
    const int row0 = by * BM;
    const int col0 = bx * BN;

    const size_t strideK2 = (size_t)K * 2;

    // ---- staging source/dest precompute (inverse-swizzled global source) ----
    const char* gAp[LA]; int lAo[LA];
#pragma unroll
    for (int i = 0; i < LA; ++i) {
        int Lp  = i * 512 + tid;
        int row = Lp >> 2, sl = Lp & 3;
        int src = sl ^ ((row >> 1) & 3);
        gAp[i] = (const char*)A + (size_t)(row0 + row) * strideK2 + src * 16;
        lAo[i] = i * 8192 + w * 1024;      // wave-uniform base + lane*16 by HW
    }
    const char* gBp[LB]; int lBo[LB];
#pragma unroll
    for (int i = 0; i < LB; ++i) {
        int Lp  = i * 512 + tid;
        int row = Lp >> 2, sl = Lp & 3;
        int src = sl ^ ((row >> 1) & 3);
        gBp[i] = (const char*)Bm + (size_t)(col0 + row) * strideK2 + src * 16;
        lBo[i] = ASZ + i * 8192 + w * 1024;
    }
    auto stage = [&](int tt) {
        char* sb = smem + (tt & 3) * SLOT;
        const size_t kb = (size_t)tt * 64;
#pragma unroll
        for (int i = 0; i < LA; ++i) gload16(gAp[i] + kb, sb + lAo[i]);
#pragma unroll
        for (int i = 0; i < LB; ++i) gload16(gBp[i] + kb, sb + lBo[i]);
    };

    // ---- swizzled fragment-read offsets (within a slot) ----
    int aRd[MR], bRd[4];
#pragma unroll
    for (int m = 0; m < MR; ++m) {
        int row = wm * (BM / 2) + m * 16 + (lane & 15);
        aRd[m] = row * 64 + (((lane >> 4) ^ ((row >> 1) & 3)) * 16);
    }
#pragma unroll
    for (int n = 0; n < 4; ++n) {
        int row = wn * 64 + n * 16 + (lane & 15);
        bRd[n] = ASZ + row * 64 + (((lane >> 4) ^ ((row >> 1) & 3)) * 16);
    }

    f32x4 acc[MR][4] = {};

    const int nt = K >> 5;                 // 64 (grad) / 128 (fwd)
    stage(0); stage(1); stage(2);          // prologue: 3 tiles in flight

    for (int t = 0; t < nt; ++t) {
        __builtin_amdgcn_s_barrier();      // B1: prev-tile reads done (WAR)
        if (t + 3 < nt) stage(t + 3);
        const int rem = nt - 1 - t;
        if constexpr (L == 4) {
            if (rem >= 3)      asm volatile("s_waitcnt vmcnt(12)" ::: "memory");
            else if (rem == 2) asm volatile("s_waitcnt vmcnt(8)"  ::: "memory");
            else if (rem == 1) asm volatile("s_waitcnt vmcnt(4)"  ::: "memory");
            else               asm volatile("s_waitcnt vmcnt(0)"  ::: "memory");
        } else {
            if (rem >= 3)      asm volatile("s_waitcnt vmcnt(9)"  ::: "memory");
            else if (rem == 2) asm volatile("s_waitcnt vmcnt(6)"  ::: "memory");
            else if (rem == 1) asm volatile("s_waitcnt vmcnt(3)"  ::: "memory");
            else               asm volatile("s_waitcnt vmcnt(0)"  ::: "memory");
        }
        __builtin_amdgcn_s_barrier();      // B2: tile t visible to all waves (RAW)

        const char* sb = smem + (t & 3) * SLOT;
        bf16x8 aF[4], bF[4];
#pragma unroll
        for (int n = 0; n < 4; ++n) bF[n] = *reinterpret_cast<const bf16x8*>(sb + bRd[n]);
#pragma unroll
        for (int m = 0; m < 4; ++m) aF[m] = *reinterpret_cast<const bf16x8*>(sb + aRd[m]);
        __builtin_amdgcn_s_setprio(1);
#pragma unroll
        for (int m = 0; m < 4; ++m)
#pragma unroll
            for (int n = 0; n < 4; ++n)
                acc[m][n] = __builtin_amdgcn_mfma_f32_16x16x32_bf16(aF[m], bF[n], acc[m][n], 0, 0, 0);
        __builtin_amdgcn_s_setprio(0);
        if constexpr (MR == 8) {
            bf16x8 aG[4];
#pragma unroll
            for (int m = 0; m < 4; ++m) aG[m] = *reinterpret_cast<const bf16x8*>(sb + aRd[m + 4]);
            __builtin_amdgcn_s_setprio(1);
#pragma unroll
            for (int m = 0; m < 4; ++m)
#pragma unroll
                for (int n = 0; n < 4; ++n)
                    acc[m + 4][n] = __builtin_amdgcn_mfma_f32_16x16x32_bf16(aG[m], bF[n], acc[m + 4][n], 0, 0, 0);
            __builtin_amdgcn_s_setprio(0);
        }
    }

    __builtin_amdgcn_s_barrier();          // all reads done; reuse LDS for epilogue

    // ---- epilogue: per-wave LDS re-layout -> coalesced I/O ----
    // MFMA C layout (m89): acc[m][n][i] -> row (lane>>4)*4+i, col n*16+(lane&15)
    float* lep = (float*)(smem + w * 4352); // [16][68] f32 per wave
    const int li = lane >> 4;
    const int lc = lane & 15;
    const int row0w = row0 + wm * (BM / 2);
    const int col0w = col0 + wn * 64;
#pragma unroll
    for (int m = 0; m < MR; ++m) {
#pragma unroll
        for (int n = 0; n < 4; ++n)
#pragma unroll
            for (int i = 0; i < 4; ++i)
                lep[(li * 4 + i) * 68 + n * 16 + lc] = acc[m][n][i];
        asm volatile("s_waitcnt lgkmcnt(0)" ::: "memory");   // cross-lane LDS dep
        __builtin_amdgcn_sched_barrier(0);
#pragma unroll
        for (int rr = 0; rr < 4; ++rr) {
            const int row = rr + li * 4;
            float4 v = *reinterpret_cast<const float4*>(&lep[row * 68 + lc * 4]);
            const size_t idx  = (size_t)(row0w + m * 16 + row) * N + col0w + lc * 4;
            const size_t idx4 = idx >> 2;
            if constexpr (EPI == 0) {
                float4 iv = reinterpret_cast<const float4*>(inb)[idx4];
                ushort4 g;
                g.x = f2bf(-0.05f * sqrtf(iv.x * iv.x + 1e-6f) * expf(-v.x));
                g.y = f2bf(-0.05f * sqrtf(iv.y * iv.y + 1e-6f) * expf(-v.y));
                g.z = f2bf(-0.05f * sqrtf(iv.z * iv.z + 1e-6f) * expf(-v.z));
                g.w = f2bf(-0.05f * sqrtf(iv.w * iv.w + 1e-6f) * expf(-v.w));
                *reinterpret_cast<ushort4*>(&Gb[idx]) = g;
            } else if constexpr (EPI == 1) {
                float4 iv = reinterpret_cast<const float4*>(inb)[idx4];
                float4 o;
                o.x = 0.05f * (1.0f + expf(-v.x)) * sqrtf(iv.x * iv.x + 1e-6f);
                o.y = 0.05f * (1.0f + expf(-v.y)) * sqrtf(iv.y * iv.y + 1e-6f);
                o.z = 0.05f * (1.0f + expf(-v.z)) * sqrtf(iv.z * iv.z + 1e-6f);
                o.w = 0.05f * (1.0f + expf(-v.w)) * sqrtf(iv.w * iv.w + 1e-6f);
                reinterpret_cast<float4*>(out)[idx4] = o;
            } else {
                float4  xv  = reinterpret_cast<const float4*>(x)[idx4];
                ushort4 a1u = *reinterpret_cast<const ushort4*>(&acc1[idx]);
                ushort4 a2u = *reinterpret_cast<const ushort4*>(&acc2[idx]);
                float xs[4] = {xv.x, xv.y, xv.z, xv.w};
                float vs[4] = {v.x, v.y, v.z, v.w};
                ushortT a1s[4] = {a1u.x, a1u.y, a1u.z, a1u.w};
                ushortT a2s[4] = {a2u.x, a2u.y, a2u.z, a2u.w};
                float xn4[4]; ushortT a1n[4], a2n[4], xbn[4];
#pragma unroll
                for (int j = 0; j < 4; ++j) {
                    float g    = vs[j] + 0.02f * xs[j] + 0.1f * xs[j] * rsqrtf(xs[j] * xs[j] + 1e-6f);
                    float a1   = 0.9f * bf2f(a1s[j]) + 0.1f * g * g;
                    float inv  = rsqrtf(a1 + 1e-8f);
                    float r_   = 0.009f * g * inv;
                    float a2   = 0.9f * bf2f(a2s[j]) - r_;
                    float cand = xs[j] - r_;
                    float t_   = 0.0009f * inv;
                    float xn   = fmaxf(cand - t_, 0.0f) + fminf(cand + t_, 0.0f) + 0.9f * a2;
                    xn4[j] = xn; a1n[j] = f2bf(a1); a2n[j] = f2bf(a2); xbn[j] = f2bf(xn);
                }
                float4 xo = {xn4[0], xn4[1], xn4[2], xn4[3]};
                reinterpret_cast<float4*>(x)[idx4] = xo;
                *reinterpret_cast<ushort4*>(&acc1[idx]) = make_ushort4(a1n[0], a1n[1], a1n[2], a1n[3]);
                *reinterpret_cast<ushort4*>(&acc2[idx]) = make_ushort4(a2n[0], a2n[1], a2n[2], a2n[3]);
                *reinterpret_cast<ushort4*>(&xb[idx])   = make_ushort4(xbn[0], xbn[1], xbn[2], xbn[3]);
            }
        }
        asm volatile("s_waitcnt lgkmcnt(0)" ::: "memory");   // reads done before next m overwrites
    }
}

extern "C" void kernel_launch(void* const* d_in, const int* in_sizes, int n_in,
                              void* d_out, int out_size, void* d_ws, size_t ws_size,
                              hipStream_t stream) {
    const float* in = (const float*)d_in[0];
    const float* W  = (const float*)d_in[1];
    float* out = (float*)d_out;
    char* ws = (char*)d_ws;

    // workspace layout — 208 MB total
    float*   x    = (float*)(ws);                              // 64 MB fp32 [4096,4096]
    ushortT* acc1 = (ushortT*)(ws + ((size_t)64  << 20));      // 32 MB bf16
    ushortT* acc2 = (ushortT*)(ws + ((size_t)96  << 20));      // 32 MB bf16
    ushortT* xb   = (ushortT*)(ws + ((size_t)128 << 20));      // 32 MB bf16 [4096,4096]
    ushortT* Wb   = (ushortT*)(ws + ((size_t)160 << 20));      // 16 MB bf16 [4096,2048]
    ushortT* WTb  = (ushortT*)(ws + ((size_t)176 << 20));      // 16 MB bf16 [2048,4096]
    ushortT* Gb   = (ushortT*)(ws + ((size_t)192 << 20));      // 16 MB bf16 [4096,2048]

    hipMemsetAsync(ws, 0, (size_t)128 << 20, stream);          // x, acc1, acc2 = 0

    prep_g0_kernel<<<dim3(B_DIM * IN_DIM / 4 / 256), dim3(256), 0, stream>>>(in, Gb);
    conv_w_kernel<<<dim3(IN_DIM / 64, OUT_DIM / 64), dim3(256), 0, stream>>>(W, Wb, WTb);

    // fwd/final: M=4096 (BM=128, 32 blk) x N=2048 (BN=256, 8 blk)  = 256 blocks
    // grad:      M=4096 (BM=256, 16 blk) x N=4096 (BN=256, 16 blk) = 256 blocks
    for (int step = 0; step < 9; ++step) {
        if (step > 0) {
            gemm_ring<0, 128><<<dim3(256), dim3(512), 0, stream>>>(
                xb, WTb, IN_DIM, OUT_DIM, in, Gb, nullptr, nullptr, nullptr, nullptr, nullptr);
        }
        gemm_ring<2, 256><<<dim3(256), dim3(512), 0, stream>>>(
            Gb, Wb, OUT_DIM, IN_DIM, nullptr, nullptr, nullptr, x, acc1, acc2, xb);
    }
    gemm_ring<1, 128><<<dim3(256), dim3(512), 0, stream>>>(
        xb, WTb, IN_DIM, OUT_DIM, in, nullptr, out, nullptr, nullptr, nullptr, nullptr);
}

// Round 5
// 1618.615 us; speedup vs baseline: 1.9579x; 1.0603x over previous
//
#include <hip/hip_runtime.h>
#include <cstdint>
#include <cstddef>

#define B_DIM   4096
#define IN_DIM  2048
#define OUT_DIM 4096

typedef __attribute__((ext_vector_type(8))) __bf16 bf16x8;
typedef __attribute__((ext_vector_type(4))) float  f32x4;
typedef unsigned short ushortT;

__device__ __forceinline__ ushortT f2bf(float f) {
    unsigned int u = __float_as_uint(f);
    u += 0x7FFFu + ((u >> 16) & 1u);          // round-to-nearest-even
    return (ushortT)(u >> 16);
}
__device__ __forceinline__ float bf2f(ushortT b) {
    return __uint_as_float(((unsigned int)b) << 16);
}

// global -> LDS direct DMA, 16 B per lane (wave-uniform LDS base, lane i at +i*16).
__device__ __forceinline__ void gload16(const void* g, void* l) {
    __builtin_amdgcn_global_load_lds(
        (const __attribute__((address_space(1))) void*)g,
        (__attribute__((address_space(3))) void*)l, 16, 0, 0);
}

// G0 = bf16(-0.05 * sqrt(in^2 + 1e-6))   (step-0 gradient: x=0 -> exp(-u)=1)
__global__ void prep_g0_kernel(const float* __restrict__ in, ushortT* __restrict__ Gb) {
    int i = blockIdx.x * 256 + threadIdx.x;
    float4 v = reinterpret_cast<const float4*>(in)[i];
    ushort4 g;
    g.x = f2bf(-0.05f * sqrtf(v.x * v.x + 1e-6f));
    g.y = f2bf(-0.05f * sqrtf(v.y * v.y + 1e-6f));
    g.z = f2bf(-0.05f * sqrtf(v.z * v.z + 1e-6f));
    g.w = f2bf(-0.05f * sqrtf(v.w * v.w + 1e-6f));
    reinterpret_cast<ushort4*>(Gb)[i] = g;
}

// Wb = bf16(W) [OUT][IN];  WTb = bf16(W^T) [IN][OUT]
__global__ void conv_w_kernel(const float* __restrict__ W, ushortT* __restrict__ Wb,
                              ushortT* __restrict__ WTb) {
    __shared__ float tile[64][65];
    const int i0 = blockIdx.x * 64;
    const int j0 = blockIdx.y * 64;
    const int c  = threadIdx.x & 63;
    const int rq = threadIdx.x >> 6;
#pragma unroll
    for (int rp = 0; rp < 16; ++rp) {
        int row = rp * 4 + rq;
        float w = W[(size_t)(j0 + row) * IN_DIM + i0 + c];
        tile[row][c] = w;
        Wb[(size_t)(j0 + row) * IN_DIM + i0 + c] = f2bf(w);
    }
    __syncthreads();
#pragma unroll
    for (int rp = 0; rp < 16; ++rp) {
        int row = rp * 4 + rq;
        WTb[(size_t)(i0 + row) * OUT_DIM + j0 + c] = f2bf(tile[c][row]);
    }
}

// ============================================================================
// Ring + register-pipelined NT GEMM: C[M,N] = A[M,K]*Bm[N,K]^T, bf16/fp32-acc.
// BN=256, BK=32, 8 waves (2M x 4N), 512 threads. Depth-4 LDS ring; stage 3
// ahead; counted vmcnt. Fragments for tile t+1 are ds_read into a register
// double-buffer DURING tile t's MFMA cluster (reads issue between B_pub and
// the MFMAs; consumed next iter). Per iter:
//   stage(t+3); vmcnt(2L|L|0); B_pub; [read a2(t), frags(t+1)]; sched_bar;
//   setprio(1); 16|32 MFMA on cur; setprio(0); B_end
// Hazards: RAW -- vmcnt+B_pub publishes tile t+1 before its reads.
//          WAR -- stage(t+3) overwrites slot t-1 only after B_end(t-1),
//                 which follows the MFMAs that consumed slot t-1's reads.
// LDS XOR-swizzle slot^=(row>>1)&3 on 16B slots (both-sides, rule #21).
// Epilogue staged via LDS -> coalesced.  State is bf16-only (xb/acc1/acc2).
// ============================================================================
template <int EPI, int BM>
__global__ __launch_bounds__(512, 1)
void gemm_ring(const ushortT* __restrict__ A, const ushortT* __restrict__ Bm,
               int N, int K,
               const float* __restrict__ inb, ushortT* __restrict__ Gb,
               float* __restrict__ out,
               ushortT* __restrict__ acc1, ushortT* __restrict__ acc2,
               ushortT* __restrict__ xb) {
    constexpr int BN   = 256;
    constexpr int ASZ  = BM * 64;          // A K-slab bytes (BM x 32 bf16)
    constexpr int BSZ  = BN * 64;
    constexpr int SLOT = ASZ + BSZ;
    constexpr int LA   = BM / 128;         // gload instrs per thread for A
    constexpr int LB   = BN / 128;         // 2
    constexpr int L    = LA + LB;          // 3 (BM=128) / 4 (BM=256)
    constexpr int MR   = BM / 32;          // per-wave M fragments (4 or 8)
    __shared__ alignas(16) char smem[4 * SLOT];

    const int tid  = threadIdx.x;
    const int lane = tid & 63;
    const int w    = tid >> 6;
    const int wm   = w >> 2;
    const int wn   = w & 3;
    const int nbx  = N / BN;
    const int nwg  = gridDim.x;
    const int cpx  = nwg >> 3;
    const int bid  = (int)blockIdx.x;
    const int swz  = (bid & 7) * cpx + (bid >> 3);   // XCD-aware bijective
    const int bx   = swz % nbx;
    const int by   = swz / nbx;
    const int row0 = by * BM;
    const int col0 = bx * BN;

    const size_t strideK2 = (size_t)K * 2;

    // ---- staging (inverse-swizzled global source; LDS dest linear) ----
    const char* gAp[LA]; int lAo[LA];
#pragma unroll
    for (int i = 0; i < LA; ++i) {
        int Lp  = i * 512 + tid;
        int row = Lp >> 2, sl = Lp & 3;
        int src = sl ^ ((row >> 1) & 3);
        gAp[i] = (const char*)A + (size_t)(row0 + row) * strideK2 + src * 16;
        lAo[i] = i * 8192 + w * 1024;
    }
    const char* gBp[LB]; int lBo[LB];
#pragma unroll
    for (int i = 0; i < LB; ++i) {
        int Lp  = i * 512 + tid;
        int row = Lp >> 2, sl = Lp & 3;
        int src = sl ^ ((row >> 1) & 3);
        gBp[i] = (const char*)Bm + (size_t)(col0 + row) * strideK2 + src * 16;
        lBo[i] = ASZ + i * 8192 + w * 1024;
    }
    auto stage = [&](int tt) {
        char* sb = smem + (tt & 3) * SLOT;
        const size_t kb = (size_t)tt * 64;
#pragma unroll
        for (int i = 0; i < LA; ++i) gload16(gAp[i] + kb, sb + lAo[i]);
#pragma unroll
        for (int i = 0; i < LB; ++i) gload16(gBp[i] + kb, sb + lBo[i]);
    };

    // ---- swizzled fragment-read offsets ----
    int aRd[MR], bRd[4];
#pragma unroll
    for (int m = 0; m < MR; ++m) {
        int row = wm * (BM / 2) + m * 16 + (lane & 15);
        aRd[m] = row * 64 + (((lane >> 4) ^ ((row >> 1) & 3)) * 16);
    }
#pragma unroll
    for (int n = 0; n < 4; ++n) {
        int row = wn * 64 + n * 16 + (lane & 15);
        bRd[n] = ASZ + row * 64 + (((lane >> 4) ^ ((row >> 1) & 3)) * 16);
    }

    f32x4 acc[MR][4] = {};
    const int nt = K >> 5;

    // ---- prologue: 3 tiles in flight; prefetch frags(0) ----
    stage(0); stage(1); stage(2);
    asm volatile("s_waitcnt vmcnt(%0)" :: "n"(2 * L) : "memory");  // tile 0 done
    __builtin_amdgcn_s_barrier();
    bf16x8 FA[8], FB[8];
#pragma unroll
    for (int m = 0; m < 4; ++m) FA[m]     = *reinterpret_cast<const bf16x8*>(smem + aRd[m]);
#pragma unroll
    for (int n = 0; n < 4; ++n) FA[4 + n] = *reinterpret_cast<const bf16x8*>(smem + bRd[n]);

    auto iter = [&](int t, bf16x8 (&cur)[8], bf16x8 (&nxt)[8]) {
        if (t + 3 < nt) stage(t + 3);
        const int rem = nt - 1 - t;
        if (rem >= 3)      asm volatile("s_waitcnt vmcnt(%0)" :: "n"(2 * L) : "memory");
        else if (rem == 2) asm volatile("s_waitcnt vmcnt(%0)" :: "n"(L)     : "memory");
        else               asm volatile("s_waitcnt vmcnt(0)"  ::: "memory");
        __builtin_amdgcn_s_barrier();                  // B_pub: tile t+1 visible
        __builtin_amdgcn_sched_barrier(0);
        const char* sbC = smem + (t & 3) * SLOT;
        const char* sbN = smem + ((t + 1) & 3) * SLOT;
        bf16x8 a2[4];
        if constexpr (MR == 8) {
#pragma unroll
            for (int m = 0; m < 4; ++m) a2[m] = *reinterpret_cast<const bf16x8*>(sbC + aRd[m + 4]);
        }
        if (rem >= 1) {
#pragma unroll
            for (int m = 0; m < 4; ++m) nxt[m]     = *reinterpret_cast<const bf16x8*>(sbN + aRd[m]);
#pragma unroll
            for (int n = 0; n < 4; ++n) nxt[4 + n] = *reinterpret_cast<const bf16x8*>(sbN + bRd[n]);
        }
        __builtin_amdgcn_sched_barrier(0);
        __builtin_amdgcn_s_setprio(1);
#pragma unroll
        for (int m = 0; m < 4; ++m)
#pragma unroll
            for (int n = 0; n < 4; ++n)
                acc[m][n] = __builtin_amdgcn_mfma_f32_16x16x32_bf16(cur[m], cur[4 + n], acc[m][n], 0, 0, 0);
        if constexpr (MR == 8) {
#pragma unroll
            for (int m = 0; m < 4; ++m)
#pragma unroll
                for (int n = 0; n < 4; ++n)
                    acc[m + 4][n] = __builtin_amdgcn_mfma_f32_16x16x32_bf16(a2[m], cur[4 + n], acc[m + 4][n], 0, 0, 0);
        }
        __builtin_amdgcn_s_setprio(0);
        __builtin_amdgcn_s_barrier();                  // B_end: WAR fence for ring
        __builtin_amdgcn_sched_barrier(0);
    };

    for (int t = 0; t < nt; t += 2) {      // nt even; static ping-pong (rule #20)
        iter(t,     FA, FB);
        iter(t + 1, FB, FA);
    }

    // ---- epilogue: per-wave LDS re-layout -> coalesced I/O ----
    // MFMA C layout (m89): acc[m][n][i] -> row (lane>>4)*4+i, col n*16+(lane&15)
    float* lep = (float*)(smem + w * 4352); // [16][68] f32 per wave
    const int li = lane >> 4;
    const int lc = lane & 15;
    const int row0w = row0 + wm * (BM / 2);
    const int col0w = col0 + wn * 64;
#pragma unroll
    for (int m = 0; m < MR; ++m) {
#pragma unroll
        for (int n = 0; n < 4; ++n)
#pragma unroll
            for (int i = 0; i < 4; ++i)
                lep[(li * 4 + i) * 68 + n * 16 + lc] = acc[m][n][i];
        asm volatile("s_waitcnt lgkmcnt(0)" ::: "memory");
        __builtin_amdgcn_sched_barrier(0);
#pragma unroll
        for (int rr = 0; rr < 4; ++rr) {
            const int row = rr + li * 4;
            float4 v = *reinterpret_cast<const float4*>(&lep[row * 68 + lc * 4]);
            const size_t idx  = (size_t)(row0w + m * 16 + row) * N + col0w + lc * 4;
            const size_t idx4 = idx >> 2;
            if constexpr (EPI == 0) {
                float4 iv = reinterpret_cast<const float4*>(inb)[idx4];
                ushort4 g;
                g.x = f2bf(-0.05f * sqrtf(iv.x * iv.x + 1e-6f) * expf(-v.x));
                g.y = f2bf(-0.05f * sqrtf(iv.y * iv.y + 1e-6f) * expf(-v.y));
                g.z = f2bf(-0.05f * sqrtf(iv.z * iv.z + 1e-6f) * expf(-v.z));
                g.w = f2bf(-0.05f * sqrtf(iv.w * iv.w + 1e-6f) * expf(-v.w));
                *reinterpret_cast<ushort4*>(&Gb[idx]) = g;
            } else if constexpr (EPI == 1) {
                float4 iv = reinterpret_cast<const float4*>(inb)[idx4];
                float4 o;
                o.x = 0.05f * (1.0f + expf(-v.x)) * sqrtf(iv.x * iv.x + 1e-6f);
                o.y = 0.05f * (1.0f + expf(-v.y)) * sqrtf(iv.y * iv.y + 1e-6f);
                o.z = 0.05f * (1.0f + expf(-v.z)) * sqrtf(iv.z * iv.z + 1e-6f);
                o.w = 0.05f * (1.0f + expf(-v.w)) * sqrtf(iv.w * iv.w + 1e-6f);
                reinterpret_cast<float4*>(out)[idx4] = o;
            } else {
                ushort4 xu  = *reinterpret_cast<const ushort4*>(&xb[idx]);
                ushort4 a1u = *reinterpret_cast<const ushort4*>(&acc1[idx]);
                ushort4 a2u = *reinterpret_cast<const ushort4*>(&acc2[idx]);
                float xs[4] = {bf2f(xu.x), bf2f(xu.y), bf2f(xu.z), bf2f(xu.w)};
                float vs[4] = {v.x, v.y, v.z, v.w};
                ushortT a1s[4] = {a1u.x, a1u.y, a1u.z, a1u.w};
                ushortT a2s[4] = {a2u.x, a2u.y, a2u.z, a2u.w};
                ushortT a1n[4], a2n[4], xbn[4];
#pragma unroll
                for (int j = 0; j < 4; ++j) {
                    float g    = vs[j] + 0.02f * xs[j] + 0.1f * xs[j] * rsqrtf(xs[j] * xs[j] + 1e-6f);
                    float a1   = 0.9f * bf2f(a1s[j]) + 0.1f * g * g;
                    float inv  = rsqrtf(a1 + 1e-8f);
                    float r_   = 0.009f * g * inv;
                    float a2   = 0.9f * bf2f(a2s[j]) - r_;
                    float cand = xs[j] - r_;
                    float t_   = 0.0009f * inv;
                    float xn   = fmaxf(cand - t_, 0.0f) + fminf(cand + t_, 0.0f) + 0.9f * a2;
                    a1n[j] = f2bf(a1); a2n[j] = f2bf(a2); xbn[j] = f2bf(xn);
                }
                *reinterpret_cast<ushort4*>(&acc1[idx]) = make_ushort4(a1n[0], a1n[1], a1n[2], a1n[3]);
                *reinterpret_cast<ushort4*>(&acc2[idx]) = make_ushort4(a2n[0], a2n[1], a2n[2], a2n[3]);
                *reinterpret_cast<ushort4*>(&xb[idx])   = make_ushort4(xbn[0], xbn[1], xbn[2], xbn[3]);
            }
        }
        asm volatile("s_waitcnt lgkmcnt(0)" ::: "memory");   // lep reads done before next m
    }
}

extern "C" void kernel_launch(void* const* d_in, const int* in_sizes, int n_in,
                              void* d_out, int out_size, void* d_ws, size_t ws_size,
                              hipStream_t stream) {
    const float* in = (const float*)d_in[0];
    const float* W  = (const float*)d_in[1];
    float* out = (float*)d_out;
    char* ws = (char*)d_ws;

    // workspace layout — 144 MB total (state first for one contiguous memset)
    ushortT* acc1 = (ushortT*)(ws);                            // 32 MB bf16 [4096,4096]
    ushortT* acc2 = (ushortT*)(ws + ((size_t)32  << 20));      // 32 MB bf16
    ushortT* xb   = (ushortT*)(ws + ((size_t)64  << 20));      // 32 MB bf16
    ushortT* Wb   = (ushortT*)(ws + ((size_t)96  << 20));      // 16 MB bf16 [4096,2048]
    ushortT* WTb  = (ushortT*)(ws + ((size_t)112 << 20));      // 16 MB bf16 [2048,4096]
    ushortT* Gb   = (ushortT*)(ws + ((size_t)128 << 20));      // 16 MB bf16 [4096,2048]

    hipMemsetAsync(ws, 0, (size_t)96 << 20, stream);           // acc1, acc2, xb = 0

    prep_g0_kernel<<<dim3(B_DIM * IN_DIM / 4 / 256), dim3(256), 0, stream>>>(in, Gb);
    conv_w_kernel<<<dim3(IN_DIM / 64, OUT_DIM / 64), dim3(256), 0, stream>>>(W, Wb, WTb);

    // fwd/final: 32x8 = 256 blocks (BM=128); grad: 16x16 = 256 blocks (BM=256)
    for (int step = 0; step < 9; ++step) {
        if (step > 0) {
            gemm_ring<0, 128><<<dim3(256), dim3(512), 0, stream>>>(
                xb, WTb, IN_DIM, OUT_DIM, in, Gb, nullptr, nullptr, nullptr, nullptr);
        }
        gemm_ring<2, 256><<<dim3(256), dim3(512), 0, stream>>>(
            Gb, Wb, OUT_DIM, IN_DIM, nullptr, nullptr, nullptr, acc1, acc2, xb);
    }
    gemm_ring<1, 128><<<dim3(256), dim3(512), 0, stream>>>(
        xb, WTb, IN_DIM, OUT_DIM, in, nullptr, out, nullptr, nullptr, nullptr);
}

// Round 6
// 1560.052 us; speedup vs baseline: 2.0314x; 1.0375x over previous
//
#include <hip/hip_runtime.h>
#include <cstdint>
#include <cstddef>

#define B_DIM   4096
#define IN_DIM  2048
#define OUT_DIM 4096

typedef __attribute__((ext_vector_type(8))) __bf16 bf16x8;
typedef __attribute__((ext_vector_type(4))) float  f32x4;
typedef unsigned short ushortT;

__device__ __forceinline__ ushortT f2bf(float f) {
    unsigned int u = __float_as_uint(f);
    u += 0x7FFFu + ((u >> 16) & 1u);          // round-to-nearest-even
    return (ushortT)(u >> 16);
}
__device__ __forceinline__ float bf2f(ushortT b) {
    return __uint_as_float(((unsigned int)b) << 16);
}

// global -> LDS direct DMA, 16 B per lane (wave-uniform LDS base, lane i at +i*16).
__device__ __forceinline__ void gload16(const void* g, void* l) {
    __builtin_amdgcn_global_load_lds(
        (const __attribute__((address_space(1))) void*)g,
        (__attribute__((address_space(3))) void*)l, 16, 0, 0);
}

// G0 = bf16(-0.05 * sqrt(in^2 + 1e-6))   (step-0 gradient: x=0 -> exp(-u)=1)
__global__ void prep_g0_kernel(const float* __restrict__ in, ushortT* __restrict__ Gb) {
    int i = blockIdx.x * 256 + threadIdx.x;
    float4 v = reinterpret_cast<const float4*>(in)[i];
    ushort4 g;
    g.x = f2bf(-0.05f * sqrtf(v.x * v.x + 1e-6f));
    g.y = f2bf(-0.05f * sqrtf(v.y * v.y + 1e-6f));
    g.z = f2bf(-0.05f * sqrtf(v.z * v.z + 1e-6f));
    g.w = f2bf(-0.05f * sqrtf(v.w * v.w + 1e-6f));
    reinterpret_cast<ushort4*>(Gb)[i] = g;
}

// Wb = bf16(W) [OUT][IN];  WTb = bf16(W^T) [IN][OUT]
__global__ void conv_w_kernel(const float* __restrict__ W, ushortT* __restrict__ Wb,
                              ushortT* __restrict__ WTb) {
    __shared__ float tile[64][65];
    const int i0 = blockIdx.x * 64;
    const int j0 = blockIdx.y * 64;
    const int c  = threadIdx.x & 63;
    const int rq = threadIdx.x >> 6;
#pragma unroll
    for (int rp = 0; rp < 16; ++rp) {
        int row = rp * 4 + rq;
        float w = W[(size_t)(j0 + row) * IN_DIM + i0 + c];
        tile[row][c] = w;
        Wb[(size_t)(j0 + row) * IN_DIM + i0 + c] = f2bf(w);
    }
    __syncthreads();
#pragma unroll
    for (int rp = 0; rp < 16; ++rp) {
        int row = rp * 4 + rq;
        WTb[(size_t)(i0 + row) * OUT_DIM + j0 + c] = f2bf(tile[c][row]);
    }
}

// ============================================================================
// Phase-interleaved NT GEMM (m201-style schedule on a ring-4 BK=32 LDS):
// C[M,N] = A[M,K]*Bm[N,K]^T, bf16 in / fp32 acc. BN=256, 8 waves (2M x 4N).
// Double-iter consumes 2 ring slots (BK=64), split into MR phases of:
//   {2 A-frag ds_reads (+4 B at slot start); 1 gload chunk (tile tt+3/tt+4);
//    lgkmcnt(0); setprio(1); 8 MFMA; setprio(0); s_barrier}
// Publish: counted vmcnt(L) + barrier at iter start (never 0 in steady loop).
// Hazards: RAW -- vmcnt(L)+barrier forces slots tt,tt+1 complete (leaves tt+2
//   in flight). WAR -- gload into slot s only issues after a barrier following
//   all lgkm0-completed reads of s (slot tt+3 = tile tt-1: reads lgkm0'd in
//   prev iter; slot tt+4 = slot tt: staged only in phases >= MR/2, after the
//   phase-(MR/2-1) barrier that follows slot-tt's last lgkm0).
// LDS XOR-swizzle slot^=(row>>1)&3 on 16B slots (both-sides, rule #21).
// Epilogue staged via LDS -> coalesced. State is bf16-only (xb/acc1/acc2).
// ============================================================================
template <int EPI, int BM>
__global__ __launch_bounds__(512, 1)
void gemm_phase(const ushortT* __restrict__ A, const ushortT* __restrict__ Bm,
                int N, int K,
                const float* __restrict__ inb, ushortT* __restrict__ Gb,
                float* __restrict__ out,
                ushortT* __restrict__ acc1, ushortT* __restrict__ acc2,
                ushortT* __restrict__ xb) {
    constexpr int BN   = 256;
    constexpr int ASZ  = BM * 64;          // A K-slab bytes (BM x 32 bf16)
    constexpr int BSZ  = BN * 64;
    constexpr int SLOT = ASZ + BSZ;
    constexpr int LA   = BM / 128;         // gload instrs per thread for A
    constexpr int LB   = BN / 128;         // 2
    constexpr int L    = LA + LB;          // 3 (BM=128) / 4 (BM=256)
    constexpr int MR   = BM / 32;          // per-wave M fragments (4 or 8)
    constexpr int HP   = MR / 2;           // phases per slot
    __shared__ alignas(16) char smem[4 * SLOT];

    const int tid  = threadIdx.x;
    const int lane = tid & 63;
    const int w    = tid >> 6;
    const int wm   = w >> 2;
    const int wn   = w & 3;
    const int nbx  = N / BN;
    const int nwg  = gridDim.x;
    const int cpx  = nwg >> 3;
    const int bid  = (int)blockIdx.x;
    const int swz  = (bid & 7) * cpx + (bid >> 3);   // XCD-aware bijective
    const int bx   = swz % nbx;
    const int by   = swz / nbx;
    const int row0 = by * BM;
    const int col0 = bx * BN;

    const size_t strideK2 = (size_t)K * 2;

    // ---- staging pointers, unified (A chunks then B chunks);
    //      inverse-swizzled global source, linear LDS dest ----
    const char* gp[L]; int lo[L];
#pragma unroll
    for (int i = 0; i < LA; ++i) {
        int Lp  = i * 512 + tid;
        int row = Lp >> 2, sl = Lp & 3;
        int src = sl ^ ((row >> 1) & 3);
        gp[i] = (const char*)A + (size_t)(row0 + row) * strideK2 + src * 16;
        lo[i] = i * 8192 + w * 1024;
    }
#pragma unroll
    for (int i = 0; i < LB; ++i) {
        int Lp  = i * 512 + tid;
        int row = Lp >> 2, sl = Lp & 3;
        int src = sl ^ ((row >> 1) & 3);
        gp[LA + i] = (const char*)Bm + (size_t)(col0 + row) * strideK2 + src * 16;
        lo[LA + i] = ASZ + i * 8192 + w * 1024;
    }
    auto stage_all = [&](int tt) {
        char* sb = smem + (tt & 3) * SLOT;
        const size_t kb = (size_t)tt * 64;
#pragma unroll
        for (int c = 0; c < L; ++c) gload16(gp[c] + kb, sb + lo[c]);
    };
    auto stage_chunk = [&](int tt, int c) {
        gload16(gp[c] + (size_t)tt * 64, smem + (tt & 3) * SLOT + lo[c]);
    };

    // ---- swizzled fragment-read offsets ----
    int aRd[MR], bRd[4];
#pragma unroll
    for (int m = 0; m < MR; ++m) {
        int row = wm * (BM / 2) + m * 16 + (lane & 15);
        aRd[m] = row * 64 + (((lane >> 4) ^ ((row >> 1) & 3)) * 16);
    }
#pragma unroll
    for (int n = 0; n < 4; ++n) {
        int row = wn * 64 + n * 16 + (lane & 15);
        bRd[n] = ASZ + row * 64 + (((lane >> 4) ^ ((row >> 1) & 3)) * 16);
    }

    f32x4 acc[MR][4] = {};
    const int nt = K >> 5;                 // even (64 grad / 128 fwd)

    stage_all(0); stage_all(1); stage_all(2);   // prologue: 3 slots in flight

    for (int tt = 0; tt < nt; tt += 2) {
        // ---- publish slots tt, tt+1 (counted vmcnt; 0 only at the tail) ----
        if (tt + 2 < nt) asm volatile("s_waitcnt vmcnt(%0)" :: "n"(L) : "memory");
        else             asm volatile("s_waitcnt vmcnt(0)"  ::: "memory");
        __builtin_amdgcn_s_barrier();
        __builtin_amdgcn_sched_barrier(0);

        bf16x8 bF[4];
#pragma unroll
        for (int p = 0; p < MR; ++p) {
            constexpr int C0 = 1, C1 = 1;   // (placeholders; chunk range below)
            const int sslot = p / HP;                      // 0 or 1
            const int mp    = p % HP;
            const char* sb  = smem + ((tt + sslot) & 3) * SLOT;
            if (mp == 0) {
#pragma unroll
                for (int n = 0; n < 4; ++n)
                    bF[n] = *reinterpret_cast<const bf16x8*>(sb + bRd[n]);
            }
            bf16x8 aF0 = *reinterpret_cast<const bf16x8*>(sb + aRd[2 * mp]);
            bf16x8 aF1 = *reinterpret_cast<const bf16x8*>(sb + aRd[2 * mp + 1]);
            // stage chunks [p*2L/MR, (p+1)*2L/MR) — chunks c<L go to tile tt+3,
            // c>=L to tile tt+4 (slot tt+4 only touched in phases >= HP).
#pragma unroll
            for (int c = p * 2 * L / MR; c < (p + 1) * 2 * L / MR; ++c) {
                const int tile = (c < L) ? (tt + 3) : (tt + 4);
                const int cc   = (c < L) ? c : c - L;
                if (tile < nt) stage_chunk(tile, cc);
            }
            asm volatile("s_waitcnt lgkmcnt(0)" ::: "memory");
            __builtin_amdgcn_sched_barrier(0);
            __builtin_amdgcn_s_setprio(1);
#pragma unroll
            for (int n = 0; n < 4; ++n)
                acc[2 * mp][n] = __builtin_amdgcn_mfma_f32_16x16x32_bf16(aF0, bF[n], acc[2 * mp][n], 0, 0, 0);
#pragma unroll
            for (int n = 0; n < 4; ++n)
                acc[2 * mp + 1][n] = __builtin_amdgcn_mfma_f32_16x16x32_bf16(aF1, bF[n], acc[2 * mp + 1][n], 0, 0, 0);
            __builtin_amdgcn_s_setprio(0);
            __builtin_amdgcn_s_barrier();
            __builtin_amdgcn_sched_barrier(0);
        }
    }

    __builtin_amdgcn_s_barrier();          // safety: all reads retired; reuse LDS

    // ---- epilogue: per-wave LDS re-layout -> coalesced I/O ----
    // MFMA C layout (m89): acc[m][n][i] -> row (lane>>4)*4+i, col n*16+(lane&15)
    float* lep = (float*)(smem + w * 4352); // [16][68] f32 per wave
    const int li = lane >> 4;
    const int lc = lane & 15;
    const int row0w = row0 + wm * (BM / 2);
    const int col0w = col0 + wn * 64;
#pragma unroll
    for (int m = 0; m < MR; ++m) {
#pragma unroll
        for (int n = 0; n < 4; ++n)
#pragma unroll
            for (int i = 0; i < 4; ++i)
                lep[(li * 4 + i) * 68 + n * 16 + lc] = acc[m][n][i];
        asm volatile("s_waitcnt lgkmcnt(0)" ::: "memory");
        __builtin_amdgcn_sched_barrier(0);
#pragma unroll
        for (int rr = 0; rr < 4; ++rr) {
            const int row = rr + li * 4;
            float4 v = *reinterpret_cast<const float4*>(&lep[row * 68 + lc * 4]);
            const size_t idx  = (size_t)(row0w + m * 16 + row) * N + col0w + lc * 4;
            const size_t idx4 = idx >> 2;
            if constexpr (EPI == 0) {
                float4 iv = reinterpret_cast<const float4*>(inb)[idx4];
                ushort4 g;
                g.x = f2bf(-0.05f * sqrtf(iv.x * iv.x + 1e-6f) * expf(-v.x));
                g.y = f2bf(-0.05f * sqrtf(iv.y * iv.y + 1e-6f) * expf(-v.y));
                g.z = f2bf(-0.05f * sqrtf(iv.z * iv.z + 1e-6f) * expf(-v.z));
                g.w = f2bf(-0.05f * sqrtf(iv.w * iv.w + 1e-6f) * expf(-v.w));
                *reinterpret_cast<ushort4*>(&Gb[idx]) = g;
            } else if constexpr (EPI == 1) {
                float4 iv = reinterpret_cast<const float4*>(inb)[idx4];
                float4 o;
                o.x = 0.05f * (1.0f + expf(-v.x)) * sqrtf(iv.x * iv.x + 1e-6f);
                o.y = 0.05f * (1.0f + expf(-v.y)) * sqrtf(iv.y * iv.y + 1e-6f);
                o.z = 0.05f * (1.0f + expf(-v.z)) * sqrtf(iv.z * iv.z + 1e-6f);
                o.w = 0.05f * (1.0f + expf(-v.w)) * sqrtf(iv.w * iv.w + 1e-6f);
                reinterpret_cast<float4*>(out)[idx4] = o;
            } else {
                ushort4 xu  = *reinterpret_cast<const ushort4*>(&xb[idx]);
                ushort4 a1u = *reinterpret_cast<const ushort4*>(&acc1[idx]);
                ushort4 a2u = *reinterpret_cast<const ushort4*>(&acc2[idx]);
                float xs[4] = {bf2f(xu.x), bf2f(xu.y), bf2f(xu.z), bf2f(xu.w)};
                float vs[4] = {v.x, v.y, v.z, v.w};
                ushortT a1s[4] = {a1u.x, a1u.y, a1u.z, a1u.w};
                ushortT a2s[4] = {a2u.x, a2u.y, a2u.z, a2u.w};
                ushortT a1n[4], a2n[4], xbn[4];
#pragma unroll
                for (int j = 0; j < 4; ++j) {
                    float g    = vs[j] + 0.02f * xs[j] + 0.1f * xs[j] * rsqrtf(xs[j] * xs[j] + 1e-6f);
                    float a1   = 0.9f * bf2f(a1s[j]) + 0.1f * g * g;
                    float inv  = rsqrtf(a1 + 1e-8f);
                    float r_   = 0.009f * g * inv;
                    float a2   = 0.9f * bf2f(a2s[j]) - r_;
                    float cand = xs[j] - r_;
                    float t_   = 0.0009f * inv;
                    float xn   = fmaxf(cand - t_, 0.0f) + fminf(cand + t_, 0.0f) + 0.9f * a2;
                    a1n[j] = f2bf(a1); a2n[j] = f2bf(a2); xbn[j] = f2bf(xn);
                }
                *reinterpret_cast<ushort4*>(&acc1[idx]) = make_ushort4(a1n[0], a1n[1], a1n[2], a1n[3]);
                *reinterpret_cast<ushort4*>(&acc2[idx]) = make_ushort4(a2n[0], a2n[1], a2n[2], a2n[3]);
                *reinterpret_cast<ushort4*>(&xb[idx])   = make_ushort4(xbn[0], xbn[1], xbn[2], xbn[3]);
            }
        }
        asm volatile("s_waitcnt lgkmcnt(0)" ::: "memory");   // lep reads done before next m
    }
}

extern "C" void kernel_launch(void* const* d_in, const int* in_sizes, int n_in,
                              void* d_out, int out_size, void* d_ws, size_t ws_size,
                              hipStream_t stream) {
    const float* in = (const float*)d_in[0];
    const float* W  = (const float*)d_in[1];
    float* out = (float*)d_out;
    char* ws = (char*)d_ws;

    // workspace layout — 144 MB total (state first for one contiguous memset)
    ushortT* acc1 = (ushortT*)(ws);                            // 32 MB bf16 [4096,4096]
    ushortT* acc2 = (ushortT*)(ws + ((size_t)32  << 20));      // 32 MB bf16
    ushortT* xb   = (ushortT*)(ws + ((size_t)64  << 20));      // 32 MB bf16
    ushortT* Wb   = (ushortT*)(ws + ((size_t)96  << 20));      // 16 MB bf16 [4096,2048]
    ushortT* WTb  = (ushortT*)(ws + ((size_t)112 << 20));      // 16 MB bf16 [2048,4096]
    ushortT* Gb   = (ushortT*)(ws + ((size_t)128 << 20));      // 16 MB bf16 [4096,2048]

    hipMemsetAsync(ws, 0, (size_t)96 << 20, stream);           // acc1, acc2, xb = 0

    prep_g0_kernel<<<dim3(B_DIM * IN_DIM / 4 / 256), dim3(256), 0, stream>>>(in, Gb);
    conv_w_kernel<<<dim3(IN_DIM / 64, OUT_DIM / 64), dim3(256), 0, stream>>>(W, Wb, WTb);

    // fwd/final: 32x8 = 256 blocks (BM=128); grad: 16x16 = 256 blocks (BM=256)
    for (int step = 0; step < 9; ++step) {
        if (step > 0) {
            gemm_phase<0, 128><<<dim3(256), dim3(512), 0, stream>>>(
                xb, WTb, IN_DIM, OUT_DIM, in, Gb, nullptr, nullptr, nullptr, nullptr);
        }
        gemm_phase<2, 256><<<dim3(256), dim3(512), 0, stream>>>(
            Gb, Wb, OUT_DIM, IN_DIM, nullptr, nullptr, nullptr, acc1, acc2, xb);
    }
    gemm_phase<1, 128><<<dim3(256), dim3(512), 0, stream>>>(
        xb, WTb, IN_DIM, OUT_DIM, in, nullptr, out, nullptr, nullptr, nullptr);
}

// Round 7
// 1533.271 us; speedup vs baseline: 2.0669x; 1.0175x over previous
//
#include <hip/hip_runtime.h>
#include <cstdint>
#include <cstddef>

#define B_DIM   4096
#define IN_DIM  2048
#define OUT_DIM 4096

typedef __attribute__((ext_vector_type(8))) __bf16 bf16x8;
typedef __attribute__((ext_vector_type(4))) float  f32x4;
typedef unsigned short ushortT;

__device__ __forceinline__ ushortT f2bf(float f) {
    unsigned int u = __float_as_uint(f);
    u += 0x7FFFu + ((u >> 16) & 1u);          // round-to-nearest-even
    return (ushortT)(u >> 16);
}
__device__ __forceinline__ float bf2f(ushortT b) {
    return __uint_as_float(((unsigned int)b) << 16);
}

// global -> LDS direct DMA, 16 B per lane (wave-uniform LDS base, lane i at +i*16).
__device__ __forceinline__ void gload16(const void* g, void* l) {
    __builtin_amdgcn_global_load_lds(
        (const __attribute__((address_space(1))) void*)g,
        (__attribute__((address_space(3))) void*)l, 16, 0, 0);
}

// G0 = bf16(-0.05 * sqrt(in^2 + 1e-6))   (step-0 gradient: x=0 -> exp(-u)=1)
__global__ void prep_g0_kernel(const float* __restrict__ in, ushortT* __restrict__ Gb) {
    int i = blockIdx.x * 256 + threadIdx.x;
    float4 v = reinterpret_cast<const float4*>(in)[i];
    ushort4 g;
    g.x = f2bf(-0.05f * sqrtf(v.x * v.x + 1e-6f));
    g.y = f2bf(-0.05f * sqrtf(v.y * v.y + 1e-6f));
    g.z = f2bf(-0.05f * sqrtf(v.z * v.z + 1e-6f));
    g.w = f2bf(-0.05f * sqrtf(v.w * v.w + 1e-6f));
    reinterpret_cast<ushort4*>(Gb)[i] = g;
}

// Wb = bf16(W) [OUT][IN];  WTb = bf16(W^T) [IN][OUT]
__global__ void conv_w_kernel(const float* __restrict__ W, ushortT* __restrict__ Wb,
                              ushortT* __restrict__ WTb) {
    __shared__ float tile[64][65];
    const int i0 = blockIdx.x * 64;
    const int j0 = blockIdx.y * 64;
    const int c  = threadIdx.x & 63;
    const int rq = threadIdx.x >> 6;
#pragma unroll
    for (int rp = 0; rp < 16; ++rp) {
        int row = rp * 4 + rq;
        float w = W[(size_t)(j0 + row) * IN_DIM + i0 + c];
        tile[row][c] = w;
        Wb[(size_t)(j0 + row) * IN_DIM + i0 + c] = f2bf(w);
    }
    __syncthreads();
#pragma unroll
    for (int rp = 0; rp < 16; ++rp) {
        int row = rp * 4 + rq;
        WTb[(size_t)(i0 + row) * OUT_DIM + j0 + c] = f2bf(tile[c][row]);
    }
}

// ============================================================================
// m201-faithful phase schedule on a ring-4 BK=32 LDS. C[M,N]=A[M,K]*Bm[N,K]^T.
// BN=256, 8 waves (2M x 4N), 512 threads. Per phase:
//   {ds_read 4 A-frags (+4 B at slot start); stage 2-3 gload chunks;
//    sched_bar; s_barrier; lgkmcnt(0); sched_bar; setprio(1); 16 MFMA;
//    setprio(0); s_barrier}
// Read latency hides under the barrier rendezvous; sibling wave on the SIMD
// issues DS while this wave runs MFMA. Publish at double-iter start =
// counted vmcnt(L) + barrier (never 0 in steady loop).
// Hazards: RAW -- publish forces all staged tiles except the newest complete.
//   WAR -- tile tt+4 (slot tt) staged only in phases >= 2, after the phase-1
//   trailing barrier that follows every wave's slot-tt lgkmcnt(0); tile tt+3
//   (slot tt-1) was lgkm0-retired in the previous double-iter.
// LDS XOR-swizzle slot^=(row>>1)&3 on 16B slots (both-sides, rule #21).
// Epilogue staged via LDS -> coalesced. State is bf16-only (xb/acc1/acc2).
// ============================================================================
#define PHASE(MB, RB, SLOTP, STTILE, C0, NC)                                   \
    {                                                                          \
        const char* sb_ = (SLOTP);                                             \
        if (RB) {                                                              \
            _Pragma("unroll")                                                  \
            for (int n = 0; n < 4; ++n)                                        \
                bF[n] = *reinterpret_cast<const bf16x8*>(sb_ + bRd[n]);        \
        }                                                                      \
        bf16x8 aF[4];                                                          \
        _Pragma("unroll")                                                      \
        for (int m = 0; m < 4; ++m)                                            \
            aF[m] = *reinterpret_cast<const bf16x8*>(sb_ + aRd[(MB) + m]);     \
        if ((STTILE) < nt) {                                                   \
            _Pragma("unroll")                                                  \
            for (int c = 0; c < (NC); ++c) stage_chunk((STTILE), (C0) + c);    \
        }                                                                      \
        __builtin_amdgcn_sched_barrier(0);                                     \
        __builtin_amdgcn_s_barrier();                                          \
        asm volatile("s_waitcnt lgkmcnt(0)" ::: "memory");                     \
        __builtin_amdgcn_sched_barrier(0);                                     \
        __builtin_amdgcn_s_setprio(1);                                         \
        _Pragma("unroll")                                                      \
        for (int m = 0; m < 4; ++m) {                                          \
            _Pragma("unroll")                                                  \
            for (int n = 0; n < 4; ++n)                                        \
                acc[(MB) + m][n] = __builtin_amdgcn_mfma_f32_16x16x32_bf16(    \
                    aF[m], bF[n], acc[(MB) + m][n], 0, 0, 0);                  \
        }                                                                      \
        __builtin_amdgcn_s_setprio(0);                                         \
        __builtin_amdgcn_s_barrier();                                          \
        __builtin_amdgcn_sched_barrier(0);                                     \
    }

template <int EPI, int BM>
__global__ __launch_bounds__(512, 1)
void gemm_phase(const ushortT* __restrict__ A, const ushortT* __restrict__ Bm,
                int N, int K,
                const float* __restrict__ inb, ushortT* __restrict__ Gb,
                float* __restrict__ out,
                ushortT* __restrict__ acc1, ushortT* __restrict__ acc2,
                ushortT* __restrict__ xb) {
    constexpr int BN   = 256;
    constexpr int ASZ  = BM * 64;          // A K-slab bytes (BM x 32 bf16)
    constexpr int BSZ  = BN * 64;
    constexpr int SLOT = ASZ + BSZ;
    constexpr int LA   = BM / 128;         // gload instrs per thread for A
    constexpr int LB   = BN / 128;         // 2
    constexpr int L    = LA + LB;          // 3 (BM=128) / 4 (BM=256)
    constexpr int MR   = BM / 32;          // per-wave M fragments (4 or 8)
    __shared__ alignas(16) char smem[4 * SLOT];

    const int tid  = threadIdx.x;
    const int lane = tid & 63;
    const int w    = tid >> 6;
    const int wm   = w >> 2;
    const int wn   = w & 3;
    const int nbx  = N / BN;
    const int nwg  = gridDim.x;
    const int cpx  = nwg >> 3;
    const int bid  = (int)blockIdx.x;
    const int swz  = (bid & 7) * cpx + (bid >> 3);   // XCD-aware bijective
    const int bx   = swz % nbx;
    const int by   = swz / nbx;
    const int row0 = by * BM;
    const int col0 = bx * BN;

    const size_t strideK2 = (size_t)K * 2;

    // ---- staging pointers (A chunks then B chunks);
    //      inverse-swizzled global source, linear LDS dest ----
    const char* gp[L]; int lo[L];
#pragma unroll
    for (int i = 0; i < LA; ++i) {
        int Lp  = i * 512 + tid;
        int row = Lp >> 2, sl = Lp & 3;
        int src = sl ^ ((row >> 1) & 3);
        gp[i] = (const char*)A + (size_t)(row0 + row) * strideK2 + src * 16;
        lo[i] = i * 8192 + w * 1024;
    }
#pragma unroll
    for (int i = 0; i < LB; ++i) {
        int Lp  = i * 512 + tid;
        int row = Lp >> 2, sl = Lp & 3;
        int src = sl ^ ((row >> 1) & 3);
        gp[LA + i] = (const char*)Bm + (size_t)(col0 + row) * strideK2 + src * 16;
        lo[LA + i] = ASZ + i * 8192 + w * 1024;
    }
    auto stage_all = [&](int tt) {
        char* sb = smem + (tt & 3) * SLOT;
        const size_t kb = (size_t)tt * 64;
#pragma unroll
        for (int c = 0; c < L; ++c) gload16(gp[c] + kb, sb + lo[c]);
    };
    auto stage_chunk = [&](int tt, int c) {
        gload16(gp[c] + (size_t)tt * 64, smem + (tt & 3) * SLOT + lo[c]);
    };

    // ---- swizzled fragment-read offsets ----
    int aRd[MR], bRd[4];
#pragma unroll
    for (int m = 0; m < MR; ++m) {
        int row = wm * (BM / 2) + m * 16 + (lane & 15);
        aRd[m] = row * 64 + (((lane >> 4) ^ ((row >> 1) & 3)) * 16);
    }
#pragma unroll
    for (int n = 0; n < 4; ++n) {
        int row = wn * 64 + n * 16 + (lane & 15);
        bRd[n] = ASZ + row * 64 + (((lane >> 4) ^ ((row >> 1) & 3)) * 16);
    }

    f32x4 acc[MR][4] = {};
    const int nt = K >> 5;                 // even (64 grad / 128 fwd)

    stage_all(0); stage_all(1); stage_all(2);   // prologue: 3 slots in flight

    for (int tt = 0; tt < nt; tt += 2) {
        // publish slots tt, tt+1: counted vmcnt (0 only at the tail) + barrier
        if (tt + 2 < nt) asm volatile("s_waitcnt vmcnt(%0)" :: "n"(L) : "memory");
        else             asm volatile("s_waitcnt vmcnt(0)"  ::: "memory");
        __builtin_amdgcn_s_barrier();
        __builtin_amdgcn_sched_barrier(0);

        const char* sb0 = smem + (tt & 3) * SLOT;
        const char* sb1 = smem + ((tt + 1) & 3) * SLOT;
        bf16x8 bF[4];
        if constexpr (MR == 8) {
            PHASE(0, true,  sb0, tt + 3, 0, 2)
            PHASE(4, false, sb0, tt + 3, 2, 2)
            PHASE(0, true,  sb1, tt + 4, 0, 2)
            PHASE(4, false, sb1, tt + 4, 2, 2)
        } else {
            PHASE(0, true,  sb0, tt + 3, 0, 3)
            PHASE(0, true,  sb1, tt + 4, 0, 3)
        }
    }

    __builtin_amdgcn_s_barrier();          // all reads retired; reuse LDS

    // ---- epilogue: per-wave LDS re-layout -> coalesced I/O ----
    // MFMA C layout (m89): acc[m][n][i] -> row (lane>>4)*4+i, col n*16+(lane&15)
    float* lep = (float*)(smem + w * 4352); // [16][68] f32 per wave
    const int li = lane >> 4;
    const int lc = lane & 15;
    const int row0w = row0 + wm * (BM / 2);
    const int col0w = col0 + wn * 64;
#pragma unroll
    for (int m = 0; m < MR; ++m) {
#pragma unroll
        for (int n = 0; n < 4; ++n)
#pragma unroll
            for (int i = 0; i < 4; ++i)
                lep[(li * 4 + i) * 68 + n * 16 + lc] = acc[m][n][i];
        asm volatile("s_waitcnt lgkmcnt(0)" ::: "memory");
        __builtin_amdgcn_sched_barrier(0);
#pragma unroll
        for (int rr = 0; rr < 4; ++rr) {
            const int row = rr + li * 4;
            float4 v = *reinterpret_cast<const float4*>(&lep[row * 68 + lc * 4]);
            const size_t idx  = (size_t)(row0w + m * 16 + row) * N + col0w + lc * 4;
            const size_t idx4 = idx >> 2;
            if constexpr (EPI == 0) {
                float4 iv = reinterpret_cast<const float4*>(inb)[idx4];
                ushort4 g;
                g.x = f2bf(-0.05f * sqrtf(iv.x * iv.x + 1e-6f) * expf(-v.x));
                g.y = f2bf(-0.05f * sqrtf(iv.y * iv.y + 1e-6f) * expf(-v.y));
                g.z = f2bf(-0.05f * sqrtf(iv.z * iv.z + 1e-6f) * expf(-v.z));
                g.w = f2bf(-0.05f * sqrtf(iv.w * iv.w + 1e-6f) * expf(-v.w));
                *reinterpret_cast<ushort4*>(&Gb[idx]) = g;
            } else if constexpr (EPI == 1) {
                float4 iv = reinterpret_cast<const float4*>(inb)[idx4];
                float4 o;
                o.x = 0.05f * (1.0f + expf(-v.x)) * sqrtf(iv.x * iv.x + 1e-6f);
                o.y = 0.05f * (1.0f + expf(-v.y)) * sqrtf(iv.y * iv.y + 1e-6f);
                o.z = 0.05f * (1.0f + expf(-v.z)) * sqrtf(iv.z * iv.z + 1e-6f);
                o.w = 0.05f * (1.0f + expf(-v.w)) * sqrtf(iv.w * iv.w + 1e-6f);
                reinterpret_cast<float4*>(out)[idx4] = o;
            } else {
                ushort4 xu  = *reinterpret_cast<const ushort4*>(&xb[idx]);
                ushort4 a1u = *reinterpret_cast<const ushort4*>(&acc1[idx]);
                ushort4 a2u = *reinterpret_cast<const ushort4*>(&acc2[idx]);
                float xs[4] = {bf2f(xu.x), bf2f(xu.y), bf2f(xu.z), bf2f(xu.w)};
                float vs[4] = {v.x, v.y, v.z, v.w};
                ushortT a1s[4] = {a1u.x, a1u.y, a1u.z, a1u.w};
                ushortT a2s[4] = {a2u.x, a2u.y, a2u.z, a2u.w};
                ushortT a1n[4], a2n[4], xbn[4];
#pragma unroll
                for (int j = 0; j < 4; ++j) {
                    float g    = vs[j] + 0.02f * xs[j] + 0.1f * xs[j] * rsqrtf(xs[j] * xs[j] + 1e-6f);
                    float a1   = 0.9f * bf2f(a1s[j]) + 0.1f * g * g;
                    float inv  = rsqrtf(a1 + 1e-8f);
                    float r_   = 0.009f * g * inv;
                    float a2   = 0.9f * bf2f(a2s[j]) - r_;
                    float cand = xs[j] - r_;
                    float t_   = 0.0009f * inv;
                    float xn   = fmaxf(cand - t_, 0.0f) + fminf(cand + t_, 0.0f) + 0.9f * a2;
                    a1n[j] = f2bf(a1); a2n[j] = f2bf(a2); xbn[j] = f2bf(xn);
                }
                *reinterpret_cast<ushort4*>(&acc1[idx]) = make_ushort4(a1n[0], a1n[1], a1n[2], a1n[3]);
                *reinterpret_cast<ushort4*>(&acc2[idx]) = make_ushort4(a2n[0], a2n[1], a2n[2], a2n[3]);
                *reinterpret_cast<ushort4*>(&xb[idx])   = make_ushort4(xbn[0], xbn[1], xbn[2], xbn[3]);
            }
        }
        asm volatile("s_waitcnt lgkmcnt(0)" ::: "memory");   // lep reads done before next m
    }
}

extern "C" void kernel_launch(void* const* d_in, const int* in_sizes, int n_in,
                              void* d_out, int out_size, void* d_ws, size_t ws_size,
                              hipStream_t stream) {
    const float* in = (const float*)d_in[0];
    const float* W  = (const float*)d_in[1];
    float* out = (float*)d_out;
    char* ws = (char*)d_ws;

    // workspace layout — 144 MB total (state first for one contiguous memset)
    ushortT* acc1 = (ushortT*)(ws);                            // 32 MB bf16 [4096,4096]
    ushortT* acc2 = (ushortT*)(ws + ((size_t)32  << 20));      // 32 MB bf16
    ushortT* xb   = (ushortT*)(ws + ((size_t)64  << 20));      // 32 MB bf16
    ushortT* Wb   = (ushortT*)(ws + ((size_t)96  << 20));      // 16 MB bf16 [4096,2048]
    ushortT* WTb  = (ushortT*)(ws + ((size_t)112 << 20));      // 16 MB bf16 [2048,4096]
    ushortT* Gb   = (ushortT*)(ws + ((size_t)128 << 20));      // 16 MB bf16 [4096,2048]

    hipMemsetAsync(ws, 0, (size_t)96 << 20, stream);           // acc1, acc2, xb = 0

    prep_g0_kernel<<<dim3(B_DIM * IN_DIM / 4 / 256), dim3(256), 0, stream>>>(in, Gb);
    conv_w_kernel<<<dim3(IN_DIM / 64, OUT_DIM / 64), dim3(256), 0, stream>>>(W, Wb, WTb);

    // fwd/final: 32x8 = 256 blocks (BM=128); grad: 16x16 = 256 blocks (BM=256)
    for (int step = 0; step < 9; ++step) {
        if (step > 0) {
            gemm_phase<0, 128><<<dim3(256), dim3(512), 0, stream>>>(
                xb, WTb, IN_DIM, OUT_DIM, in, Gb, nullptr, nullptr, nullptr, nullptr);
        }
        gemm_phase<2, 256><<<dim3(256), dim3(512), 0, stream>>>(
            Gb, Wb, OUT_DIM, IN_DIM, nullptr, nullptr, nullptr, acc1, acc2, xb);
    }
    gemm_phase<1, 128><<<dim3(256), dim3(512), 0, stream>>>(
        xb, WTb, IN_DIM, OUT_DIM, in, nullptr, out, nullptr, nullptr, nullptr);
}